// Round 18
// baseline (109.343 us; speedup 1.0000x reference)
//
#include <hip/hip_runtime.h>
#include <math.h>

#define NN 50000
#define NE 800000
#define BSH 7               // bucket = dst >> 7 (128 nodes/bucket)
#define NBUCK 391           // ceil(50000/128)
#define CAP 4096            // per-bucket capacity (mean ~2046+pads, max ~3500)
#define CHUNK 4096          // edges per bscatter chunk
#define NCH ((NE + CHUNK - 1) / CHUNK)   // 196
#define K1B 782             // k1 blocks in merged kernel
#define EPT2 8              // edges per thread in merged bscatter (CHUNK/512)
#define SENT 50000          // sentinel node: Qh[SENT][*] = +inf (prescaled domain -> sig 0)
#define NL2E -1.4426950408889634f   // -log2(e): sigmoid(x)=rcp(1+exp2(-x*log2e))

typedef float4 f4;
typedef float2 f2;
typedef unsigned short u16;
typedef unsigned int u32;

__device__ __forceinline__ float sigf(float x) {          // plain sigmoid (k1's C)
    return __builtin_amdgcn_rcpf(1.0f + __expf(-x));
}

// prescaled sigmoid: y = -(x)*log2e already applied -> rcp(1 + 2^y)
__device__ __forceinline__ float sigf2(float y) {
    float e;
    asm("v_exp_f32 %0, %1" : "=v"(e) : "v"(y));
    return __builtin_amdgcn_rcpf(1.0f + e);
}

__device__ __forceinline__ u16 f32_to_bf16_rne(float f) {
    unsigned u = __float_as_uint(f);
    u += 0x7FFFu + ((u >> 16) & 1u);
    return (u16)(u >> 16);
}

// ---------------- Merged K1 + bscatter (independent work, one launch) -------
// P' = -log2e*(z@W1^T+bn); Qh' = bf16(-log2e*(z@W2^T)) -- prescaled for sigf2.
#define K1_WFLOATS (3 * 32 * 64 * 2)           // 12288 floats = 48KB
__global__ __launch_bounds__(512, 4) void k1_sc(
    const float* __restrict__ z,
    const float* __restrict__ Wc, const float* __restrict__ bc,
    const float* __restrict__ Wn, const float* __restrict__ bn,
    float* __restrict__ P, u16* __restrict__ Qh, float* __restrict__ C,
    const int* __restrict__ esrc, const int* __restrict__ edst,
    int* __restrict__ gcur, u32* __restrict__ ebuf)
{
    const int tid = threadIdx.x;
    if (blockIdx.x < K1B) {
        __shared__ float sh[K1_WFLOATS + 8 * 256];  // 48KB weights + 8KB tiles
        f2* w2 = (f2*)sh;
        for (int j = tid; j < 3 * 32 * 64; j += 512) {
            const int m = j >> 11, r = j & 2047;
            const int k2 = r >> 6, h = r & 63;
            const float* s = (m == 0) ? (Wc + h * 64 + 2 * k2)
                                      : (Wn + h * 128 + (m - 1) * 64 + 2 * k2);
            w2[(m * 32 + k2) * 64 + h] = *(const f2*)s;
        }
        __syncthreads();

        const int lane = tid & 63;
        const int wid  = tid >> 6;
        f4* tile = (f4*)(sh + K1_WFLOATS) + wid * 64;
        const f2* wl0 = w2;
        const f2* wl1 = w2 + 32 * 64;
        const f2* wl2 = w2 + 2 * 32 * 64;
        const float bcur = bc[lane], bnbr = bn[lane];

        const int gw = blockIdx.x * 8 + wid;
        const int nw = K1B * 8;
        for (int chunk = gw; chunk < NN / 4; chunk += nw) {
            const int n0 = chunk * 4;
            tile[lane] = *(const f4*)(z + n0 * 64 + lane * 4);
            float a0[4], a1[4], a2[4];
            #pragma unroll
            for (int ni = 0; ni < 4; ++ni) { a0[ni] = 0.f; a1[ni] = 0.f; a2[ni] = 0.f; }
            #pragma unroll 2
            for (int k4 = 0; k4 < 16; ++k4) {
                const f2 w0a = wl0[(2 * k4) * 64 + lane], w0b = wl0[(2 * k4 + 1) * 64 + lane];
                const f2 w1a = wl1[(2 * k4) * 64 + lane], w1b = wl1[(2 * k4 + 1) * 64 + lane];
                const f2 w2a = wl2[(2 * k4) * 64 + lane], w2b = wl2[(2 * k4 + 1) * 64 + lane];
                #pragma unroll
                for (int ni = 0; ni < 4; ++ni) {
                    const f4 zz = tile[ni * 16 + k4];  // uniform addr -> LDS broadcast
                    a0[ni] = fmaf(w0b.y, zz.w, fmaf(w0b.x, zz.z, fmaf(w0a.y, zz.y, fmaf(w0a.x, zz.x, a0[ni]))));
                    a1[ni] = fmaf(w1b.y, zz.w, fmaf(w1b.x, zz.z, fmaf(w1a.y, zz.y, fmaf(w1a.x, zz.x, a1[ni]))));
                    a2[ni] = fmaf(w2b.y, zz.w, fmaf(w2b.x, zz.z, fmaf(w2a.y, zz.y, fmaf(w2a.x, zz.x, a2[ni]))));
                }
            }
            #pragma unroll
            for (int ni = 0; ni < 4; ++ni) {
                const int n = n0 + ni;
                C[n * 64 + lane]  = sigf(a0[ni] + bcur);
                P[n * 64 + lane]  = (a1[ni] + bnbr) * NL2E;
                Qh[n * 64 + lane] = f32_to_bf16_rne(a2[ni] * NL2E);
            }
        }
    } else {
        // first scatter block also writes the sentinel Q row (+inf bf16)
        if (blockIdx.x == K1B && tid < 64) Qh[(size_t)SENT * 64 + tid] = 0x7F80u;

        __shared__ int cnt[NBUCK];
        __shared__ int gbase[NBUCK];
        __shared__ int lcur[NBUCK];
        for (int i = tid; i < NBUCK; i += 512) cnt[i] = 0;
        __syncthreads();

        const int base = (blockIdx.x - K1B) * CHUNK;
        u32 ent[EPT2];
        int nb[EPT2];
        #pragma unroll
        for (int t = 0; t < EPT2; ++t) {
            const int e = base + t * 512 + tid;
            if (e < NE) {
                const int d = edst[e], s = esrc[e];
                const int b = d >> BSH;
                ent[t] = ((u32)(d & 127) << 16) | (u32)s;
                nb[t] = b;
                atomicAdd(&cnt[b], 1);
            } else {
                nb[t] = -1;
            }
        }
        __syncthreads();
        for (int i = tid; i < NBUCK; i += 512) {
            gbase[i] = cnt[i] ? atomicAdd(&gcur[i], cnt[i]) : 0;
            lcur[i] = 0;
        }
        __syncthreads();
        #pragma unroll
        for (int t = 0; t < EPT2; ++t) {
            if (nb[t] >= 0) {
                const int li = atomicAdd(&lcur[nb[t]], 1);
                ebuf[nb[t] * CAP + gbase[nb[t]] + li] = ent[t];
            }
        }
    }
}

// One block per 128-node bucket. Node slot = max(24, round8(deg)) so every
// node supports one fixed unpredicated 24-gather round; pads = SENT.
__global__ __launch_bounds__(256) void k_bsort(const int* __restrict__ gcur,
                                               const u32* __restrict__ ebuf,
                                               u32* __restrict__ bd,
                                               u16* __restrict__ ss)
{
    __shared__ int hist[128];
    __shared__ int lcur[128];
    __shared__ int ps[128];
    __shared__ int tot;
    const int b = blockIdx.x;
    const int ecnt = gcur[b];
    const int e0 = b * CAP;
    const int n0 = b << BSH;
    const int t = threadIdx.x;

    if (t < 128) hist[t] = 0;
    __syncthreads();
    for (int j = t; j < ecnt; j += 256)
        atomicAdd(&hist[(ebuf[e0 + j] >> 16) & 127], 1);
    __syncthreads();
    if (t < 128) {
        const int a = hist[t];
        ps[t] = (a <= 24) ? 24 : ((a + 7) & ~7);   // slot size
    }
    __syncthreads();
    for (int o = 1; o < 128; o <<= 1) {
        int v = 0;
        if (t < 128 && t >= o) v = ps[t - o];
        __syncthreads();
        if (t < 128 && t >= o) ps[t] += v;
        __syncthreads();
    }
    if (t < 128) {
        const int a = hist[t];
        const int r = (a <= 24) ? 24 : ((a + 7) & ~7);
        const int excl = ps[t] - r;                // exclusive slot offset
        lcur[t] = excl;
        const int n = n0 + t;
        if (n < NN) bd[n] = ((u32)(e0 + excl) << 8) | (u32)a;
        if (t == 127) tot = ps[127];
    }
    __syncthreads();
    const int zw = (tot + 48) >> 1;                // sentinel fill + guard
    u32* ssw = (u32*)(ss + e0);
    for (int j = t; j < zw; j += 256) ssw[j] = 0xC350C350u;  // SENT|SENT
    __syncthreads();
    for (int j = t; j < ecnt; j += 256) {
        const u32 ent = ebuf[e0 + j];
        const int p = atomicAdd(&lcur[(ent >> 16) & 127], 1);
        ss[e0 + p] = (u16)(ent & 0xFFFFu);
    }
}

// Extra-round helper (rare dg>24 tail): NQ in {8,16,24} sentinel-padded.
template<int NQ>
__device__ __forceinline__ void round_g(const u16* __restrict__ ip,
                                        const u16* __restrict__ qbl,
                                        float p, float& acc)
{
    uint4 iv0, iv1, iv2;
    asm volatile("global_load_dwordx4 %0, %1, off" : "=v"(iv0) : "v"(ip));
    if constexpr (NQ >= 16)
        asm volatile("global_load_dwordx4 %0, %1, off offset:16" : "=v"(iv1) : "v"(ip));
    if constexpr (NQ >= 24)
        asm volatile("global_load_dwordx4 %0, %1, off offset:32" : "=v"(iv2) : "v"(ip));
    asm volatile("s_waitcnt vmcnt(0)" ::: "memory");
    __builtin_amdgcn_sched_barrier(0);
    u32 wv[NQ / 2];
    wv[0] = iv0.x; wv[1] = iv0.y; wv[2] = iv0.z; wv[3] = iv0.w;
    if constexpr (NQ >= 16) { wv[4] = iv1.x; wv[5] = iv1.y; wv[6] = iv1.z; wv[7] = iv1.w; }
    if constexpr (NQ >= 24) { wv[8] = iv2.x; wv[9] = iv2.y; wv[10] = iv2.z; wv[11] = iv2.w; }
    u32 q[NQ];
    #pragma unroll
    for (int t8 = 0; t8 < NQ / 2; ++t8) {
        const u16* aL = qbl + ((wv[t8] & 0xFFFFu) << 6);
        const u16* aH = qbl + ((wv[t8] >> 16) << 6);
        asm volatile("global_load_ushort %0, %1, off" : "=v"(q[2 * t8])     : "v"(aL));
        asm volatile("global_load_ushort %0, %1, off" : "=v"(q[2 * t8 + 1]) : "v"(aH));
    }
    asm volatile("s_waitcnt vmcnt(0)" ::: "memory");
    __builtin_amdgcn_sched_barrier(0);
    #pragma unroll
    for (int t = 0; t < NQ; ++t)
        acc += sigf2(p + __uint_as_float(q[t] << 16));
}

// ---------------- Fused K2+K3: cross-node pipelined gathers -----------------
// Per node i: [vmcnt(0): idx_i ready] -> issue 24 gathers -> issue idx_{i+1}
// -> vmcnt(3) (gathers done, idx_{i+1} flies under compute) -> 24 sigf2.
// Every node's first round is a fixed unpredicated 24 (bsort guarantees
// slot >= 24, sentinel-padded). dg>24 (~2%) takes serial extra rounds.
__global__ __launch_bounds__(512, 8) void k23(
    const u32* __restrict__ bd, const u16* __restrict__ ss,
    const float* __restrict__ P, const u16* __restrict__ Qh,
    const float* __restrict__ C, const float* __restrict__ Wo,
    const float* __restrict__ bo, float* __restrict__ out)
{
    __shared__ u32 w1u[32 * 64];                // C-part Wo: bf16x2 (8KB)
    __shared__ f2  w2f[32 * 64];                // NB-part Wo: f32x2 (16KB)
    __shared__ float tiles[8 * 512];            // per-wave [4 nodes][C | NB]
    const int tid = threadIdx.x;
    for (int j = tid; j < 32 * 64; j += 512) {
        const int k2 = j >> 6, d = j & 63;
        const f2 wc = *(const f2*)(Wo + d * 128 + 2 * k2);
        w1u[k2 * 64 + d] = ((u32)f32_to_bf16_rne(wc.y) << 16) | (u32)f32_to_bf16_rne(wc.x);
        w2f[k2 * 64 + d] = *(const f2*)(Wo + d * 128 + 64 + 2 * k2);
    }
    __syncthreads();

    const int lane = tid & 63;
    const int wid  = tid >> 6;
    float* tile = tiles + wid * 512;
    const f4* t4 = (const f4*)tile;
    const u16* qbl = Qh + lane;
    const float bout = bo[lane];

    for (int chunk = blockIdx.x * 8 + wid; chunk < NN / 4; chunk += gridDim.x * 8) {
        const int n0 = chunk * 4;
        int beg[4], dg[4];
        float pv[4];
        #pragma unroll
        for (int i = 0; i < 4; ++i) {
            const u32 w = bd[n0 + i];
            beg[i] = __builtin_amdgcn_readfirstlane((int)(w >> 8));
            dg[i]  = __builtin_amdgcn_readfirstlane((int)(w & 255u));
            pv[i]  = P[(n0 + i) * 64 + lane];
            tile[i * 128 + lane] = C[(n0 + i) * 64 + lane];
        }

        uint4 iv0, iv1, iv2;
        {   // prologue: idx for node 0
            const u16* ip = ss + beg[0];
            asm volatile("global_load_dwordx4 %0, %1, off" : "=v"(iv0) : "v"(ip));
            asm volatile("global_load_dwordx4 %0, %1, off offset:16" : "=v"(iv1) : "v"(ip));
            asm volatile("global_load_dwordx4 %0, %1, off offset:32" : "=v"(iv2) : "v"(ip));
        }
        #pragma unroll
        for (int i = 0; i < 4; ++i) {
            asm volatile("s_waitcnt vmcnt(0)" ::: "memory");   // idx_i ready
            __builtin_amdgcn_sched_barrier(0);
            u32 q[24];
            // 24 gathers, addresses straight from iv fields (keeps VGPR low)
            #define G2(w, k) { \
                const u16* aL = qbl + (((w) & 0xFFFFu) << 6); \
                const u16* aH = qbl + (((w) >> 16) << 6); \
                asm volatile("global_load_ushort %0, %1, off" : "=v"(q[k])     : "v"(aL)); \
                asm volatile("global_load_ushort %0, %1, off" : "=v"(q[(k)+1]) : "v"(aH)); }
            G2(iv0.x, 0)  G2(iv0.y, 2)  G2(iv0.z, 4)  G2(iv0.w, 6)
            G2(iv1.x, 8)  G2(iv1.y, 10) G2(iv1.z, 12) G2(iv1.w, 14)
            G2(iv2.x, 16) G2(iv2.y, 18) G2(iv2.z, 20) G2(iv2.w, 22)
            #undef G2
            if (i < 3) {                                       // prefetch idx_{i+1}
                const u16* ip = ss + beg[i + 1];
                asm volatile("global_load_dwordx4 %0, %1, off" : "=v"(iv0) : "v"(ip));
                asm volatile("global_load_dwordx4 %0, %1, off offset:16" : "=v"(iv1) : "v"(ip));
                asm volatile("global_load_dwordx4 %0, %1, off offset:32" : "=v"(iv2) : "v"(ip));
                asm volatile("s_waitcnt vmcnt(3)" ::: "memory");  // gathers done, idx flying
            } else {
                asm volatile("s_waitcnt vmcnt(0)" ::: "memory");
            }
            __builtin_amdgcn_sched_barrier(0);
            float acc = 0.f;
            #pragma unroll
            for (int t = 0; t < 24; ++t)
                acc += sigf2(pv[i] + __uint_as_float(q[t] << 16));
            if (dg[i] > 24) {                    // rare serial extra rounds
                const int rdg = (dg[i] + 7) & ~7;
                int jb = 24;
                for (; jb + 24 <= rdg; jb += 24)
                    round_g<24>(ss + beg[i] + jb, qbl, pv[i], acc);
                const int rem = rdg - jb;
                if (rem == 16)     round_g<16>(ss + beg[i] + jb, qbl, pv[i], acc);
                else if (rem == 8) round_g<8>(ss + beg[i] + jb, qbl, pv[i], acc);
            }
            tile[i * 128 + 64 + lane] = acc;     // wave-internal: no barrier
        }

        float a2[4] = {0.f, 0.f, 0.f, 0.f};
        // C-part contraction (bf16 weights; |C| <= 1)
        #pragma unroll 2
        for (int k4 = 0; k4 < 16; ++k4) {
            const u32 ua = w1u[(2 * k4) * 64 + lane];
            const u32 ub = w1u[(2 * k4 + 1) * 64 + lane];
            const float wa0 = __uint_as_float(ua << 16);
            const float wa1 = __uint_as_float(ua & 0xFFFF0000u);
            const float wb0 = __uint_as_float(ub << 16);
            const float wb1 = __uint_as_float(ub & 0xFFFF0000u);
            #pragma unroll
            for (int i = 0; i < 4; ++i) {
                const f4 hv = t4[i * 32 + k4];   // uniform addr -> LDS broadcast
                a2[i] = fmaf(wb1, hv.w, fmaf(wb0, hv.z, fmaf(wa1, hv.y, fmaf(wa0, hv.x, a2[i]))));
            }
        }
        // NB-part contraction (f32 weights; |NB| up to ~35)
        #pragma unroll 2
        for (int k4 = 0; k4 < 16; ++k4) {
            const f2 wa = w2f[(2 * k4) * 64 + lane];
            const f2 wb = w2f[(2 * k4 + 1) * 64 + lane];
            #pragma unroll
            for (int i = 0; i < 4; ++i) {
                const f4 hv = t4[i * 32 + 16 + k4];
                a2[i] = fmaf(wb.y, hv.w, fmaf(wb.x, hv.z, fmaf(wa.y, hv.y, fmaf(wa.x, hv.x, a2[i]))));
            }
        }
        #pragma unroll
        for (int i = 0; i < 4; ++i)
            out[(n0 + i) * 64 + lane] = tanhf(a2[i] + bout);
    }
}

extern "C" void kernel_launch(void* const* d_in, const int* in_sizes, int n_in,
                              void* d_out, int out_size, void* d_ws, size_t ws_size,
                              hipStream_t stream) {
    const float* z  = (const float*)d_in[0];
    const int* esrc = (const int*)d_in[1];
    const int* edst = (const int*)d_in[2];
    const float* Wc = (const float*)d_in[3];
    const float* bc = (const float*)d_in[4];
    const float* Wn = (const float*)d_in[5];
    const float* bn = (const float*)d_in[6];
    const float* Wo = (const float*)d_in[7];
    const float* bo = (const float*)d_in[8];
    float* out = (float*)d_out;

    float* P   = (float*)d_ws;                   // [NN*64] f32 (prescaled)
    float* C   = P + (size_t)NN * 64;            // [NN*64] f32
    u16* Qh    = (u16*)(C + (size_t)NN * 64);    // [(NN+1)*64] bf16 (prescaled + sentinel)
    u32* bd    = (u32*)(Qh + (size_t)(NN + 1) * 64); // [NN] packed (beg<<8)|deg
    int* gcur  = (int*)(bd + NN + 64);           // [512]
    u32* ebuf  = (u32*)(gcur + 512);             // [NBUCK*CAP] packed entries
    u16* ss    = (u16*)(ebuf + (size_t)NBUCK * CAP); // [NBUCK*CAP + pad] u16

    hipMemsetAsync(gcur, 0, 512 * sizeof(int), stream);
    k1_sc<<<K1B + NCH, 512, 0, stream>>>(z, Wc, bc, Wn, bn, P, Qh, C,
                                         esrc, edst, gcur, ebuf);
    k_bsort<<<NBUCK, 256, 0, stream>>>(gcur, ebuf, bd, ss);
    k23<<<1563, 512, 0, stream>>>(bd, ss, P, Qh, C, Wo, bo, out);
}

// Round 19
// 102.665 us; speedup vs baseline: 1.0650x; 1.0650x over previous
//
#include <hip/hip_runtime.h>
#include <math.h>

#define NN 50000
#define NE 800000
#define BSH 7               // bucket = dst >> 7 (128 nodes/bucket)
#define NBUCK 391           // ceil(50000/128)
#define CAP 4096            // per-bucket capacity
#define CHUNK 4096          // edges per bscatter chunk
#define NCH ((NE + CHUNK - 1) / CHUNK)   // 196
#define K1B 782             // k1 blocks in merged kernel
#define EPT2 8              // edges per thread in merged bscatter (CHUNK/512)
#define SENT 50000          // sentinel node: Qh[SENT][*] = +inf (prescaled -> sig 0)
#define NL2E -1.4426950408889634f   // -log2(e)

typedef float4 f4;
typedef float2 f2;
typedef unsigned short u16;
typedef unsigned int u32;

__device__ __forceinline__ float sigf(float x) {          // plain sigmoid (k1's C)
    return __builtin_amdgcn_rcpf(1.0f + __expf(-x));
}

// prescaled sigmoid: y = -x*log2e already applied -> rcp(1 + 2^y)
__device__ __forceinline__ float sigf2(float y) {
    float e;
    asm("v_exp_f32 %0, %1" : "=v"(e) : "v"(y));
    return __builtin_amdgcn_rcpf(1.0f + e);
}

__device__ __forceinline__ u16 f32_to_bf16_rne(float f) {
    unsigned u = __float_as_uint(f);
    u += 0x7FFFu + ((u >> 16) & 1u);
    return (u16)(u >> 16);
}

// ---------------- Merged K1 + bscatter (independent work, one launch) -------
// P' = -log2e*(z@W1^T+bn); Qh' = bf16(-log2e*(z@W2^T)) -- prescaled for sigf2.
#define K1_WFLOATS (3 * 32 * 64 * 2)           // 12288 floats = 48KB
__global__ __launch_bounds__(512, 4) void k1_sc(
    const float* __restrict__ z,
    const float* __restrict__ Wc, const float* __restrict__ bc,
    const float* __restrict__ Wn, const float* __restrict__ bn,
    float* __restrict__ P, u16* __restrict__ Qh, float* __restrict__ C,
    const int* __restrict__ esrc, const int* __restrict__ edst,
    int* __restrict__ gcur, u32* __restrict__ ebuf)
{
    const int tid = threadIdx.x;
    if (blockIdx.x < K1B) {
        __shared__ float sh[K1_WFLOATS + 8 * 256];  // 48KB weights + 8KB tiles
        f2* w2 = (f2*)sh;
        for (int j = tid; j < 3 * 32 * 64; j += 512) {
            const int m = j >> 11, r = j & 2047;
            const int k2 = r >> 6, h = r & 63;
            const float* s = (m == 0) ? (Wc + h * 64 + 2 * k2)
                                      : (Wn + h * 128 + (m - 1) * 64 + 2 * k2);
            w2[(m * 32 + k2) * 64 + h] = *(const f2*)s;
        }
        __syncthreads();

        const int lane = tid & 63;
        const int wid  = tid >> 6;
        f4* tile = (f4*)(sh + K1_WFLOATS) + wid * 64;
        const f2* wl0 = w2;
        const f2* wl1 = w2 + 32 * 64;
        const f2* wl2 = w2 + 2 * 32 * 64;
        const float bcur = bc[lane], bnbr = bn[lane];

        const int gw = blockIdx.x * 8 + wid;
        const int nw = K1B * 8;
        for (int chunk = gw; chunk < NN / 4; chunk += nw) {
            const int n0 = chunk * 4;
            tile[lane] = *(const f4*)(z + n0 * 64 + lane * 4);
            float a0[4], a1[4], a2[4];
            #pragma unroll
            for (int ni = 0; ni < 4; ++ni) { a0[ni] = 0.f; a1[ni] = 0.f; a2[ni] = 0.f; }
            #pragma unroll 2
            for (int k4 = 0; k4 < 16; ++k4) {
                const f2 w0a = wl0[(2 * k4) * 64 + lane], w0b = wl0[(2 * k4 + 1) * 64 + lane];
                const f2 w1a = wl1[(2 * k4) * 64 + lane], w1b = wl1[(2 * k4 + 1) * 64 + lane];
                const f2 w2a = wl2[(2 * k4) * 64 + lane], w2b = wl2[(2 * k4 + 1) * 64 + lane];
                #pragma unroll
                for (int ni = 0; ni < 4; ++ni) {
                    const f4 zz = tile[ni * 16 + k4];  // uniform addr -> LDS broadcast
                    a0[ni] = fmaf(w0b.y, zz.w, fmaf(w0b.x, zz.z, fmaf(w0a.y, zz.y, fmaf(w0a.x, zz.x, a0[ni]))));
                    a1[ni] = fmaf(w1b.y, zz.w, fmaf(w1b.x, zz.z, fmaf(w1a.y, zz.y, fmaf(w1a.x, zz.x, a1[ni]))));
                    a2[ni] = fmaf(w2b.y, zz.w, fmaf(w2b.x, zz.z, fmaf(w2a.y, zz.y, fmaf(w2a.x, zz.x, a2[ni]))));
                }
            }
            #pragma unroll
            for (int ni = 0; ni < 4; ++ni) {
                const int n = n0 + ni;
                C[n * 64 + lane]  = sigf(a0[ni] + bcur);
                P[n * 64 + lane]  = (a1[ni] + bnbr) * NL2E;
                Qh[n * 64 + lane] = f32_to_bf16_rne(a2[ni] * NL2E);
            }
        }
    } else {
        // first scatter block also writes the sentinel Q row (+inf bf16)
        if (blockIdx.x == K1B && tid < 64) Qh[(size_t)SENT * 64 + tid] = 0x7F80u;

        __shared__ int cnt[NBUCK];
        __shared__ int gbase[NBUCK];
        __shared__ int lcur[NBUCK];
        for (int i = tid; i < NBUCK; i += 512) cnt[i] = 0;
        __syncthreads();

        const int base = (blockIdx.x - K1B) * CHUNK;
        u32 ent[EPT2];
        int nb[EPT2];
        #pragma unroll
        for (int t = 0; t < EPT2; ++t) {
            const int e = base + t * 512 + tid;
            if (e < NE) {
                const int d = edst[e], s = esrc[e];
                const int b = d >> BSH;
                ent[t] = ((u32)(d & 127) << 16) | (u32)s;
                nb[t] = b;
                atomicAdd(&cnt[b], 1);
            } else {
                nb[t] = -1;
            }
        }
        __syncthreads();
        for (int i = tid; i < NBUCK; i += 512) {
            gbase[i] = cnt[i] ? atomicAdd(&gcur[i], cnt[i]) : 0;
            lcur[i] = 0;
        }
        __syncthreads();
        #pragma unroll
        for (int t = 0; t < EPT2; ++t) {
            if (nb[t] >= 0) {
                const int li = atomicAdd(&lcur[nb[t]], 1);
                ebuf[nb[t] * CAP + gbase[nb[t]] + li] = ent[t];
            }
        }
    }
}

// One block per 128-node bucket. Node segments rounded to 8 entries (16B);
// pad slots = SENT (gather hits +inf row -> contributes exactly 0).
__global__ __launch_bounds__(256) void k_bsort(const int* __restrict__ gcur,
                                               const u32* __restrict__ ebuf,
                                               u32* __restrict__ bd,
                                               u16* __restrict__ ss)
{
    __shared__ int hist[128];
    __shared__ int lcur[128];
    __shared__ int ps[128];
    __shared__ int tot;
    const int b = blockIdx.x;
    const int ecnt = gcur[b];
    const int e0 = b * CAP;
    const int n0 = b << BSH;
    const int t = threadIdx.x;

    if (t < 128) hist[t] = 0;
    __syncthreads();
    for (int j = t; j < ecnt; j += 256)
        atomicAdd(&hist[(ebuf[e0 + j] >> 16) & 127], 1);
    __syncthreads();
    if (t < 128) ps[t] = (hist[t] + 7) & ~7;     // rounded slot size
    __syncthreads();
    for (int o = 1; o < 128; o <<= 1) {
        int v = 0;
        if (t < 128 && t >= o) v = ps[t - o];
        __syncthreads();
        if (t < 128 && t >= o) ps[t] += v;
        __syncthreads();
    }
    if (t < 128) {
        const int a = hist[t];
        const int r = (a + 7) & ~7;
        const int excl = ps[t] - r;              // exclusive rounded offset
        lcur[t] = excl;
        const int n = n0 + t;
        if (n < NN) bd[n] = ((u32)(e0 + excl) << 8) | (u32)a;
        if (t == 127) tot = ps[127];
    }
    __syncthreads();
    const int zw = (tot + 48) >> 1;              // sentinel fill + guard
    u32* ssw = (u32*)(ss + e0);
    for (int j = t; j < zw; j += 256) ssw[j] = 0xC350C350u;  // SENT|SENT
    __syncthreads();
    for (int j = t; j < ecnt; j += 256) {
        const u32 ent = ebuf[e0 + j];
        const int p = atomicAdd(&lcur[(ent >> 16) & 127], 1);
        ss[e0 + p] = (u16)(ent & 0xFFFFu);
    }
}

// One gather round, 2 edges per slot word. NW slot words in {4,8,12} =
// {8,16,24} edges. Lanes 0-31 gather the even edge's row (4B/lane), lanes
// 32-63 the odd edge's. One idx-wait + one gather-wait per round.
template<int NW>
__device__ __forceinline__ void round_g2(const u16* __restrict__ ip,
                                         const u16* __restrict__ qbl2,
                                         int sel, f2 p2,
                                         float& acc0, float& acc1)
{
    uint4 iv0, iv1, iv2;
    asm volatile("global_load_dwordx4 %0, %1, off" : "=v"(iv0) : "v"(ip));
    if constexpr (NW >= 8)
        asm volatile("global_load_dwordx4 %0, %1, off offset:16" : "=v"(iv1) : "v"(ip));
    if constexpr (NW >= 12)
        asm volatile("global_load_dwordx4 %0, %1, off offset:32" : "=v"(iv2) : "v"(ip));
    asm volatile("s_waitcnt vmcnt(0)" ::: "memory");
    __builtin_amdgcn_sched_barrier(0);
    u32 wv[NW];
    wv[0] = iv0.x; wv[1] = iv0.y; wv[2] = iv0.z; wv[3] = iv0.w;
    if constexpr (NW >= 8)  { wv[4] = iv1.x; wv[5] = iv1.y; wv[6] = iv1.z; wv[7] = iv1.w; }
    if constexpr (NW >= 12) { wv[8] = iv2.x; wv[9] = iv2.y; wv[10] = iv2.z; wv[11] = iv2.w; }
    u32 q[NW];
    #pragma unroll
    for (int w = 0; w < NW; ++w) {
        const u32 sv = (wv[w] >> sel) & 0xFFFFu;       // lane<32: even edge; else odd
        const u16* a = qbl2 + (sv << 6);
        asm volatile("global_load_dword %0, %1, off" : "=v"(q[w]) : "v"(a));
    }
    asm volatile("s_waitcnt vmcnt(0)" ::: "memory");
    __builtin_amdgcn_sched_barrier(0);
    #pragma unroll
    for (int w = 0; w < NW; ++w) {
        const float lo = __uint_as_float(q[w] << 16);          // h = 2*(lane&31)
        const float hi = __uint_as_float(q[w] & 0xFFFF0000u);  // h = 2*(lane&31)+1
        acc0 += sigf2(p2.x + lo);
        acc1 += sigf2(p2.y + hi);
    }
}

// ---------------- Fused K2+K3: one wave per 4 dst nodes ---------------------
// Mixed-precision Wo in LDS (bf16 C-part 8KB + f32 NB-part 16KB) + 16KB
// tiles = 40KB -> 4 blocks/CU. Per node: exact-rdg 2-edge-slot rounds,
// shfl_xor(32) half-wave combine, then 4-node-amortized contraction.
__global__ __launch_bounds__(512, 8) void k23(
    const u32* __restrict__ bd, const u16* __restrict__ ss,
    const float* __restrict__ P, const u16* __restrict__ Qh,
    const float* __restrict__ C, const float* __restrict__ Wo,
    const float* __restrict__ bo, float* __restrict__ out)
{
    __shared__ u32 w1u[32 * 64];                // C-part Wo: bf16x2 (8KB)
    __shared__ f2  w2f[32 * 64];                // NB-part Wo: f32x2 (16KB)
    __shared__ float tiles[8 * 512];            // per-wave [4 nodes][C | NB]
    const int tid = threadIdx.x;
    for (int j = tid; j < 32 * 64; j += 512) {
        const int k2 = j >> 6, d = j & 63;
        const f2 wc = *(const f2*)(Wo + d * 128 + 2 * k2);
        w1u[k2 * 64 + d] = ((u32)f32_to_bf16_rne(wc.y) << 16) | (u32)f32_to_bf16_rne(wc.x);
        w2f[k2 * 64 + d] = *(const f2*)(Wo + d * 128 + 64 + 2 * k2);
    }
    __syncthreads();

    const int lane = tid & 63;
    const int wid  = tid >> 6;
    float* tile = tiles + wid * 512;
    const f4* t4 = (const f4*)tile;
    const int sel = (lane >= 32) ? 16 : 0;
    const u16* qbl2 = Qh + (lane & 31) * 2;     // lane covers 2 bf16 of each row
    const float bout = bo[lane];

    for (int chunk = blockIdx.x * 8 + wid; chunk < NN / 4; chunk += gridDim.x * 8) {
        const int n0 = chunk * 4;
        #pragma unroll
        for (int i = 0; i < 4; ++i) {
            const int n = n0 + i;
            const u32 w = bd[n];
            const int beg = __builtin_amdgcn_readfirstlane((int)(w >> 8));
            const int dg  = __builtin_amdgcn_readfirstlane((int)(w & 255u));
            const int rdg = (dg + 7) & ~7;
            const f2 p2 = *(const f2*)(P + n * 64 + 2 * (lane & 31));
            tile[i * 128 + lane] = C[n * 64 + lane];
            float acc0 = 0.f, acc1 = 0.f;

            int jb = 0;
            for (; jb + 24 <= rdg; jb += 24)
                round_g2<12>(ss + beg + jb, qbl2, sel, p2, acc0, acc1);
            const int rem = rdg - jb;            // 0, 8, or 16 (wave-uniform)
            if (rem == 16)     round_g2<8>(ss + beg + jb, qbl2, sel, p2, acc0, acc1);
            else if (rem == 8) round_g2<4>(ss + beg + jb, qbl2, sel, p2, acc0, acc1);

            // combine half-waves: lanes l and l+32 hold the same h pair
            const float s0 = __shfl_xor(acc0, 32, 64);
            const float s1 = __shfl_xor(acc1, 32, 64);
            if (lane < 32) {
                f2 v; v.x = acc0 + s0; v.y = acc1 + s1;
                *(f2*)(tile + i * 128 + 64 + 2 * lane) = v;   // wave-internal
            }
        }

        float a2[4] = {0.f, 0.f, 0.f, 0.f};
        // C-part contraction (bf16 weights; |C| <= 1)
        #pragma unroll 2
        for (int k4 = 0; k4 < 16; ++k4) {
            const u32 ua = w1u[(2 * k4) * 64 + lane];
            const u32 ub = w1u[(2 * k4 + 1) * 64 + lane];
            const float wa0 = __uint_as_float(ua << 16);
            const float wa1 = __uint_as_float(ua & 0xFFFF0000u);
            const float wb0 = __uint_as_float(ub << 16);
            const float wb1 = __uint_as_float(ub & 0xFFFF0000u);
            #pragma unroll
            for (int i = 0; i < 4; ++i) {
                const f4 hv = t4[i * 32 + k4];   // uniform addr -> LDS broadcast
                a2[i] = fmaf(wb1, hv.w, fmaf(wb0, hv.z, fmaf(wa1, hv.y, fmaf(wa0, hv.x, a2[i]))));
            }
        }
        // NB-part contraction (f32 weights; |NB| up to ~35)
        #pragma unroll 2
        for (int k4 = 0; k4 < 16; ++k4) {
            const f2 wa = w2f[(2 * k4) * 64 + lane];
            const f2 wb = w2f[(2 * k4 + 1) * 64 + lane];
            #pragma unroll
            for (int i = 0; i < 4; ++i) {
                const f4 hv = t4[i * 32 + 16 + k4];
                a2[i] = fmaf(wb.y, hv.w, fmaf(wb.x, hv.z, fmaf(wa.y, hv.y, fmaf(wa.x, hv.x, a2[i]))));
            }
        }
        #pragma unroll
        for (int i = 0; i < 4; ++i)
            out[(n0 + i) * 64 + lane] = tanhf(a2[i] + bout);
    }
}

extern "C" void kernel_launch(void* const* d_in, const int* in_sizes, int n_in,
                              void* d_out, int out_size, void* d_ws, size_t ws_size,
                              hipStream_t stream) {
    const float* z  = (const float*)d_in[0];
    const int* esrc = (const int*)d_in[1];
    const int* edst = (const int*)d_in[2];
    const float* Wc = (const float*)d_in[3];
    const float* bc = (const float*)d_in[4];
    const float* Wn = (const float*)d_in[5];
    const float* bn = (const float*)d_in[6];
    const float* Wo = (const float*)d_in[7];
    const float* bo = (const float*)d_in[8];
    float* out = (float*)d_out;

    float* P   = (float*)d_ws;                   // [NN*64] f32 (prescaled)
    float* C   = P + (size_t)NN * 64;            // [NN*64] f32
    u16* Qh    = (u16*)(C + (size_t)NN * 64);    // [(NN+1)*64] bf16 (prescaled + sentinel)
    u32* bd    = (u32*)(Qh + (size_t)(NN + 1) * 64); // [NN] packed (beg<<8)|deg
    int* gcur  = (int*)(bd + NN + 64);           // [512]
    u32* ebuf  = (u32*)(gcur + 512);             // [NBUCK*CAP] packed entries
    u16* ss    = (u16*)(ebuf + (size_t)NBUCK * CAP); // [NBUCK*CAP + pad] u16

    hipMemsetAsync(gcur, 0, 512 * sizeof(int), stream);
    k1_sc<<<K1B + NCH, 512, 0, stream>>>(z, Wc, bc, Wn, bn, P, Qh, C,
                                         esrc, edst, gcur, ebuf);
    k_bsort<<<NBUCK, 256, 0, stream>>>(gcur, ebuf, bd, ss);
    k23<<<1563, 512, 0, stream>>>(bd, ss, P, Qh, C, Wo, bo, out);
}